// Round 4
// baseline (424.731 us; speedup 1.0000x reference)
//
#include <hip/hip_runtime.h>
#include <hip/hip_bf16.h>

// Linear attention (Shen 2018), B=2, N=16384, D=512, H=8, DK=64.
// Round 4: barrier-free phase1 (per-wave direct-global MFMA fragments, private
// LDS transposes), one-barrier phase3 with 64-row chunks.

using u16 = unsigned short;
typedef __attribute__((ext_vector_type(8))) short bf16x8;
typedef __attribute__((ext_vector_type(4))) float f32x4;

#define D_MODEL 512
#define SEQ 16384
#define ROWS 32768

// ---- ws layout (bytes); total 72,089,600 (known-safe vs prior rounds) ----
#define PART_OFF 0u            // bf16 [1024][8][64][64] = 67,108,864
#define SUMS_OFF 67108864u     // f32  [1024][8][64]     = 2,097,152
#define CTX_OFF  69206016u     // f32  [16][64][64]      = 262,144
#define WTK_OFF  69468160u     // bf16 512x512           = 524,288
#define WTV_OFF  69992448u
#define WTQ_OFF  70516736u
#define MBIGT_OFF 71041024u    // bf16 [2][512][512]     = 1,048,576
#define WS_NEEDED 72089600u

__device__ __forceinline__ float bf2f(u16 u) {
  union { unsigned int i; float f; } x; x.i = ((unsigned int)u) << 16; return x.f;
}
__device__ __forceinline__ u16 f2bf(float f) {
  union { float ff; unsigned int i; } x; x.ff = f;
  unsigned int r = x.i + 0x7fffu + ((x.i >> 16) & 1u);  // RNE
  return (u16)(r >> 16);
}
__device__ __forceinline__ unsigned int pk2(float lo, float hi) {
  union { __hip_bfloat162 h; unsigned int u; } x;
  x.h = __float22bfloat162_rn(float2{lo, hi});  // v_cvt_pk_bf16_f32 (RNE)
  return x.u;
}
__device__ __forceinline__ bf16x8 cvt8(float4 a, float4 b) {
  union { bf16x8 v; unsigned int u[4]; } x;
  x.u[0] = pk2(a.x, a.y); x.u[1] = pk2(a.z, a.w);
  x.u[2] = pk2(b.x, b.y); x.u[3] = pk2(b.z, b.w);
  return x.v;
}
// swizzled 16B LDS read: row-major tile, byte XOR ((row&mask)<<4)
__device__ __forceinline__ bf16x8 ldsrd(const u16* base, int row, int rowbytes,
                                        int kbyte, int mask) {
  return *(const bf16x8*)((const char*)base + row * rowbytes + (kbyte ^ ((row & mask) << 4)));
}

// ---------------- transpose+convert: out[c][r] (bf16) = in[r][c] (f32) ------
__launch_bounds__(256)
__global__ void wcvt_kernel(const float* __restrict__ in, u16* __restrict__ out) {
  __shared__ float S[64][65];
  const int t = threadIdx.x;
  const int i0 = blockIdx.y << 6, j0 = blockIdx.x << 6;
#pragma unroll
  for (int ii = 0; ii < 4; ++ii) {
    const int idx = t + ii * 256;
    const int r = idx >> 4, c4 = (idx & 15) << 2;
    const float4 v = *(const float4*)(in + (i0 + r) * D_MODEL + j0 + c4);
    S[r][c4] = v.x; S[r][c4 + 1] = v.y; S[r][c4 + 2] = v.z; S[r][c4 + 3] = v.w;
  }
  __syncthreads();
#pragma unroll
  for (int ii = 0; ii < 4; ++ii) {
    const int idx = t + ii * 256;
    const int c = idx >> 4, r4 = (idx & 15) << 2;
    ushort4 o;
    o.x = f2bf(S[r4][c]); o.y = f2bf(S[r4 + 1][c]);
    o.z = f2bf(S[r4 + 2][c]); o.w = f2bf(S[r4 + 3][c]);
    *(ushort4*)(out + (j0 + c) * D_MODEL + i0 + r4) = o;
  }
}

// ---------------- phase 1: barrier-free fused K/V projection + E^T V --------
// grid 2048: chunk = blk>>1 (32 rows), head-group = blk&1; 4 waves = 4 heads.
#define P1_LOAD(ks, A, B, src, WTh)                                            \
  {                                                                            \
    _Pragma("unroll") for (int mf = 0; mf < 2; ++mf) {                         \
      const float* ap = src + (size_t)(n0 + mf * 16 + lc) * D_MODEL + (ks) * 32 + g * 8; \
      A[mf][0] = *(const float4*)ap; A[mf][1] = *(const float4*)(ap + 4);      \
    }                                                                          \
    _Pragma("unroll") for (int nf = 0; nf < 4; ++nf)                           \
      B[nf] = *(const bf16x8*)(WTh + (size_t)(nf * 16 + lc) * D_MODEL + (ks) * 32 + g * 8); \
  }
#define P1_MFMA(A, B)                                                          \
  {                                                                            \
    bf16x8 af0 = cvt8(A[0][0], A[0][1]);                                       \
    bf16x8 af1 = cvt8(A[1][0], A[1][1]);                                       \
    _Pragma("unroll") for (int nf = 0; nf < 4; ++nf) {                         \
      acc[0][nf] = __builtin_amdgcn_mfma_f32_16x16x32_bf16(af0, B[nf], acc[0][nf], 0, 0, 0); \
      acc[1][nf] = __builtin_amdgcn_mfma_f32_16x16x32_bf16(af1, B[nf], acc[1][nf], 0, 0, 0); \
    }                                                                          \
  }

__launch_bounds__(256, 4)
__global__ void phase1_kernel(const float* __restrict__ key, const float* __restrict__ value,
                              const u16* __restrict__ WTk, const u16* __restrict__ WTv,
                              const float* __restrict__ bkp, const float* __restrict__ bvp,
                              u16* __restrict__ part, float* __restrict__ sums) {
  __shared__ __align__(16) u16 smem[16384];  // 32KB: ET[4][2048] | VT[4][2048]
  const int t = threadIdx.x;
  const int lane = t & 63, w = t >> 6;
  const int g = lane >> 4, lc = lane & 15;
  const int chunk = (int)blockIdx.x >> 1;
  const int h = ((int)blockIdx.x & 1) * 4 + w;  // head 0..7
  const int n0 = chunk * 32;
  u16* ETw = smem + w * 2048;                   // [64 d][32 n], rows 64B, swz mask 3
  u16* VTw = smem + 8192 + w * 2048;
  const u16* WThk = WTk + (size_t)h * 64 * D_MODEL;
  const u16* WThv = WTv + (size_t)h * 64 * D_MODEL;

  f32x4 acc[2][4];
  float4 A0[2][2], A1[2][2];
  bf16x8 B0[4], B1[4];

  // ================= E = exp(K@Wk + bk) =================
#pragma unroll
  for (int m = 0; m < 2; ++m)
#pragma unroll
    for (int n = 0; n < 4; ++n) acc[m][n] = (f32x4){0.f, 0.f, 0.f, 0.f};
  P1_LOAD(0, A0, B0, key, WThk);
#pragma unroll
  for (int ks = 0; ks < 16; ks += 2) {
    if (ks + 1 < 16) P1_LOAD(ks + 1, A1, B1, key, WThk);
    P1_MFMA(A0, B0);
    if (ks + 2 < 16) P1_LOAD(ks + 2, A0, B0, key, WThk);
    P1_MFMA(A1, B1);
  }
  {
#pragma unroll
    for (int nf = 0; nf < 4; ++nf) {
      const float bb = bkp[h * 64 + nf * 16 + lc];
      float s = 0.f;
#pragma unroll
      for (int m = 0; m < 2; ++m)
#pragma unroll
        for (int r = 0; r < 4; ++r) {
          const float v = __expf(acc[m][nf][r] + bb);
          acc[m][nf][r] = v; s += v;
        }
      s += __shfl_xor(s, 16); s += __shfl_xor(s, 32);
      const int d = nf * 16 + lc;
      if (g == 0) sums[(size_t)(chunk * 8 + h) * 64 + d] = s;
#pragma unroll
      for (int m = 0; m < 2; ++m) {
        const uint2 pw = make_uint2(pk2(acc[m][nf][0], acc[m][nf][1]),
                                    pk2(acc[m][nf][2], acc[m][nf][3]));
        *(uint2*)((char*)ETw + d * 64 + ((m * 32 + g * 8) ^ ((d & 3) << 4))) = pw;
      }
    }
  }
  // ================= Vp = V@Wv + bv =================
#pragma unroll
  for (int m = 0; m < 2; ++m)
#pragma unroll
    for (int n = 0; n < 4; ++n) acc[m][n] = (f32x4){0.f, 0.f, 0.f, 0.f};
  P1_LOAD(0, A0, B0, value, WThv);
#pragma unroll
  for (int ks = 0; ks < 16; ks += 2) {
    if (ks + 1 < 16) P1_LOAD(ks + 1, A1, B1, value, WThv);
    P1_MFMA(A0, B0);
    if (ks + 2 < 16) P1_LOAD(ks + 2, A0, B0, value, WThv);
    P1_MFMA(A1, B1);
  }
  {
#pragma unroll
    for (int nf = 0; nf < 4; ++nf) {
      const float bb = bvp[h * 64 + nf * 16 + lc];
      const int e = nf * 16 + lc;
#pragma unroll
      for (int m = 0; m < 2; ++m) {
        const uint2 pw = make_uint2(pk2(acc[m][nf][0] + bb, acc[m][nf][1] + bb),
                                    pk2(acc[m][nf][2] + bb, acc[m][nf][3] + bb));
        *(uint2*)((char*)VTw + e * 64 + ((m * 32 + g * 8) ^ ((e & 3) << 4))) = pw;
      }
    }
  }
  // ================= partial[d][e] = E^T V (k = 32 rows) =================
  // per-wave-private LDS: compiler inserts lgkmcnt waits; no barrier needed.
  {
    bf16x8 paf[4], pbf[4];
#pragma unroll
    for (int dm = 0; dm < 4; ++dm) paf[dm] = ldsrd(ETw, dm * 16 + lc, 64, g * 16, 3);
#pragma unroll
    for (int em = 0; em < 4; ++em) pbf[em] = ldsrd(VTw, em * 16 + lc, 64, g * 16, 3);
    u16* pp = part + (size_t)(chunk * 8 + h) * 4096;
#pragma unroll
    for (int dm = 0; dm < 4; ++dm)
#pragma unroll
      for (int em = 0; em < 4; ++em) {
        f32x4 pacc = __builtin_amdgcn_mfma_f32_16x16x32_bf16(paf[dm], pbf[em],
                       (f32x4){0.f, 0.f, 0.f, 0.f}, 0, 0, 0);
#pragma unroll
        for (int r = 0; r < 4; ++r)
          pp[(dm * 16 + g * 4 + r) * 64 + em * 16 + lc] = f2bf(pacc[r]);
      }
  }
}

// ---------------- phase 2: reduce partials -> ctx ---------------------------
__launch_bounds__(256)
__global__ void reduce_kernel(const u16* __restrict__ part, const float* __restrict__ sums,
                              float* __restrict__ ctx) {
  const int dg = blockIdx.x, bh = blockIdx.y;
  const int b = bh >> 3, h = bh & 7;
  const int t = threadIdx.x, dl = t >> 6, e = t & 63;
  const int d = dg * 4 + dl;
  float a = 0.f;
#pragma unroll 8
  for (int k = 0; k < 512; ++k) {
    const int gb = b * 512 + k;
    a += bf2f(part[(size_t)(gb * 8 + h) * 4096 + d * 64 + e]);
  }
  float s = 0.f;
#pragma unroll
  for (int i = 0; i < 8; ++i) {
    const int gb = b * 512 + e + i * 64;
    s += sums[(size_t)(gb * 8 + h) * 64 + d];
  }
#pragma unroll
  for (int m = 1; m < 64; m <<= 1) s += __shfl_xor(s, m);
  ctx[(size_t)bh * 4096 + d * 64 + e] = a / s;
}

// -------- MbigT[b][c][h*64+d] (bf16) = sum_e ctx[b,h,d,e] * Wo[h*64+e][c] ---
__launch_bounds__(256)
__global__ void mbigT_kernel(const float* __restrict__ ctx, const float* __restrict__ Wo,
                             u16* __restrict__ MbigT) {
  __shared__ float Clds[64][65];
  __shared__ float Wlds2[64][64];
  const int t = threadIdx.x;
  const int tx = t & 15, ty = t >> 4;
  const int cc = blockIdx.x;
  const int bh = blockIdx.y;
  const int b = bh >> 3, h = bh & 7;
  const float* ch = ctx + bh * 4096;
  for (int i4 = t; i4 < 1024; i4 += 256) {
    const int r = i4 >> 4, c = (i4 & 15) << 2;
    const float4 v = *(const float4*)(ch + (r << 6) + c);
    Clds[r][c] = v.x; Clds[r][c + 1] = v.y; Clds[r][c + 2] = v.z; Clds[r][c + 3] = v.w;
    const float4 wv = *(const float4*)(Wo + (h * 64 + r) * D_MODEL + cc * 64 + c);
    Wlds2[r][c] = wv.x; Wlds2[r][c + 1] = wv.y; Wlds2[r][c + 2] = wv.z; Wlds2[r][c + 3] = wv.w;
  }
  __syncthreads();
  float acc[4][4] = {};
#pragma unroll 8
  for (int k = 0; k < 64; ++k) {
    float a[4], wv[4];
#pragma unroll
    for (int i = 0; i < 4; ++i) a[i] = Clds[(ty << 2) + i][k];
#pragma unroll
    for (int j = 0; j < 4; ++j) wv[j] = Wlds2[k][(tx << 2) + j];
#pragma unroll
    for (int i = 0; i < 4; ++i)
#pragma unroll
      for (int j = 0; j < 4; ++j) acc[i][j] = fmaf(a[i], wv[j], acc[i][j]);
  }
  u16* mp = MbigT + b * D_MODEL * D_MODEL;
#pragma unroll
  for (int i = 0; i < 4; ++i)
#pragma unroll
    for (int j = 0; j < 4; ++j)
      mp[(cc * 64 + (tx << 2) + j) * D_MODEL + h * 64 + (ty << 2) + i] = f2bf(acc[i][j]);
}

// ---------------- phase 3: fused Q proj/softmax + output GEMM (1 barrier) ---
// grid 512: 64-row chunks; 8 waves = 8 heads.
__launch_bounds__(512, 4)
__global__ void phase3_kernel(const float* __restrict__ query, const u16* __restrict__ WTq,
                              const float* __restrict__ bqp, const u16* __restrict__ MbigT,
                              const float* __restrict__ bop, float* __restrict__ out) {
  __shared__ __align__(16) u16 P[32768];  // [64 n][512 d], rows 1024B, swz mask 7
  const int t = threadIdx.x;
  const int lane = t & 63, w = t >> 6;
  const int g = lane >> 4, lc = lane & 15;
  const int chunk = blockIdx.x;
  const int n0 = chunk * 64;
  const int b = chunk >> 8;
  const int c0 = w * 64;

  // ---- S^T = WqT_h @ Q^T : acc[mf][nf], d = c0+mf*16+g*4+r, n = nf*16+lc
  f32x4 acc[4][4];
#pragma unroll
  for (int m = 0; m < 4; ++m)
#pragma unroll
    for (int n = 0; n < 4; ++n) acc[m][n] = (f32x4){0.f, 0.f, 0.f, 0.f};
#pragma unroll 2
  for (int ks = 0; ks < 16; ++ks) {
    bf16x8 af[4], bfr[4];
#pragma unroll
    for (int mf = 0; mf < 4; ++mf)
      af[mf] = *(const bf16x8*)(WTq + (size_t)(c0 + mf * 16 + lc) * D_MODEL + ks * 32 + g * 8);
#pragma unroll
    for (int nf = 0; nf < 4; ++nf) {
      const float* qp = query + (size_t)(n0 + nf * 16 + lc) * D_MODEL + ks * 32 + g * 8;
      bfr[nf] = cvt8(*(const float4*)qp, *(const float4*)(qp + 4));
    }
#pragma unroll
    for (int mf = 0; mf < 4; ++mf)
#pragma unroll
      for (int nf = 0; nf < 4; ++nf)
        acc[mf][nf] = __builtin_amdgcn_mfma_f32_16x16x32_bf16(af[mf], bfr[nf], acc[mf][nf], 0, 0, 0);
  }
  // ---- softmax over d (per n), * 1/8, bf16 -> P_lds ----
  {
    float bqv[4][4];
#pragma unroll
    for (int m = 0; m < 4; ++m)
#pragma unroll
      for (int r = 0; r < 4; ++r) bqv[m][r] = bqp[c0 + m * 16 + g * 4 + r];
#pragma unroll
    for (int nf = 0; nf < 4; ++nf) {
      float mx = -3.0e38f;
#pragma unroll
      for (int m = 0; m < 4; ++m)
#pragma unroll
        for (int r = 0; r < 4; ++r) {
          const float v = acc[m][nf][r] + bqv[m][r];
          acc[m][nf][r] = v; mx = fmaxf(mx, v);
        }
      mx = fmaxf(mx, __shfl_xor(mx, 16)); mx = fmaxf(mx, __shfl_xor(mx, 32));
      float s = 0.f;
#pragma unroll
      for (int m = 0; m < 4; ++m)
#pragma unroll
        for (int r = 0; r < 4; ++r) {
          const float e = __expf(acc[m][nf][r] - mx);
          acc[m][nf][r] = e; s += e;
        }
      s += __shfl_xor(s, 16); s += __shfl_xor(s, 32);
      const float f = 0.125f / s;
      const int n = nf * 16 + lc;
#pragma unroll
      for (int m = 0; m < 4; ++m) {
        const uint2 pw = make_uint2(pk2(acc[m][nf][0] * f, acc[m][nf][1] * f),
                                    pk2(acc[m][nf][2] * f, acc[m][nf][3] * f));
        *(uint2*)((char*)P + n * 1024 + ((w * 128 + m * 32 + g * 8) ^ ((n & 7) << 4))) = pw;
      }
    }
  }
  __syncthreads();  // the only barrier
  // ---- out^T = MbigT[b] @ P^T : oc[mf][nf], c = c0+mf*16+g*4+r, n = nf*16+lc
  f32x4 oc[4][4];
#pragma unroll
  for (int m = 0; m < 4; ++m)
#pragma unroll
    for (int n = 0; n < 4; ++n) oc[m][n] = (f32x4){0.f, 0.f, 0.f, 0.f};
  const u16* MT = MbigT + (size_t)b * D_MODEL * D_MODEL;
#pragma unroll 2
  for (int ks = 0; ks < 16; ++ks) {
    bf16x8 af[4], bfr[4];
#pragma unroll
    for (int mf = 0; mf < 4; ++mf)
      af[mf] = *(const bf16x8*)(MT + (size_t)(c0 + mf * 16 + lc) * D_MODEL + ks * 32 + g * 8);
#pragma unroll
    for (int nf = 0; nf < 4; ++nf) bfr[nf] = ldsrd(P, nf * 16 + lc, 1024, ks * 64 + g * 16, 7);
#pragma unroll
    for (int mf = 0; mf < 4; ++mf)
#pragma unroll
      for (int nf = 0; nf < 4; ++nf)
        oc[mf][nf] = __builtin_amdgcn_mfma_f32_16x16x32_bf16(af[mf], bfr[nf], oc[mf][nf], 0, 0, 0);
  }
  {
    float bov[4][4];
#pragma unroll
    for (int m = 0; m < 4; ++m)
#pragma unroll
      for (int r = 0; r < 4; ++r) bov[m][r] = bop[c0 + m * 16 + g * 4 + r];
#pragma unroll
    for (int mf = 0; mf < 4; ++mf)
#pragma unroll
      for (int nf = 0; nf < 4; ++nf) {
        float4 o;
        o.x = oc[mf][nf][0] + bov[mf][0]; o.y = oc[mf][nf][1] + bov[mf][1];
        o.z = oc[mf][nf][2] + bov[mf][2]; o.w = oc[mf][nf][3] + bov[mf][3];
        *(float4*)(out + (size_t)(n0 + nf * 16 + lc) * D_MODEL + c0 + mf * 16 + g * 4) = o;
      }
  }
}

__global__ void sentinel_kernel(float* out) { out[0] = 1.0e9f; }

extern "C" void kernel_launch(void* const* d_in, const int* in_sizes, int n_in,
                              void* d_out, int out_size, void* d_ws, size_t ws_size,
                              hipStream_t stream) {
  const float* query = (const float*)d_in[0];
  const float* key   = (const float*)d_in[1];
  const float* value = (const float*)d_in[2];
  const float* Wq = (const float*)d_in[3];
  const float* bq = (const float*)d_in[4];
  const float* Wk = (const float*)d_in[5];
  const float* bk = (const float*)d_in[6];
  const float* Wv = (const float*)d_in[7];
  const float* bv = (const float*)d_in[8];
  const float* Wo = (const float*)d_in[9];
  const float* bo = (const float*)d_in[10];
  float* out = (float*)d_out;
  char* ws = (char*)d_ws;

  if (ws_size < (size_t)WS_NEEDED) {
    sentinel_kernel<<<1, 1, 0, stream>>>(out);
    return;
  }

  u16* part   = (u16*)(ws + PART_OFF);
  float* sums = (float*)(ws + SUMS_OFF);
  float* ctx  = (float*)(ws + CTX_OFF);
  u16* WTk    = (u16*)(ws + WTK_OFF);
  u16* WTv    = (u16*)(ws + WTV_OFF);
  u16* WTq    = (u16*)(ws + WTQ_OFF);
  u16* MbigT  = (u16*)(ws + MBIGT_OFF);

  const dim3 blk256(256), gw(8, 8);
  wcvt_kernel<<<gw, blk256, 0, stream>>>(Wk, WTk);
  wcvt_kernel<<<gw, blk256, 0, stream>>>(Wv, WTv);
  wcvt_kernel<<<gw, blk256, 0, stream>>>(Wq, WTq);
  phase1_kernel<<<2048, 256, 0, stream>>>(key, value, WTk, WTv, bk, bv, part, sums);
  reduce_kernel<<<dim3(16, 16), blk256, 0, stream>>>(part, sums, ctx);
  mbigT_kernel<<<dim3(8, 16), blk256, 0, stream>>>(ctx, Wo, MbigT);
  phase3_kernel<<<512, 512, 0, stream>>>(query, WTq, bq, MbigT, bo, out);
}

// Round 6
// 318.194 us; speedup vs baseline: 1.3348x; 1.3348x over previous
//
#include <hip/hip_runtime.h>
#include <hip/hip_bf16.h>

// Linear attention (Shen 2018), B=2, N=16384, D=512, H=8, DK=64.
// Round 6: R5 with the reduce-grid bug fixed (dim3(4,16) -> dim3(16,16);
// R5 only produced e in 0..15 of ctx, leaving 3/4 of the context stale).
//   phase1: K-GEMM ∥ V-GEMM in one 8-stage loop, dist-2 reg prefetch,
//           1 barrier/stage; per-wave E^T/V^T LDS; partial (E^T V) -> [e][d].
//   reduce: 2-level, 8B-coalesced.
//   phase3: Q-GEMM with same pipeline; in-reg softmax; P LDS; out-GEMM.

using u16 = unsigned short;
typedef __attribute__((ext_vector_type(8))) short bf16x8;
typedef __attribute__((ext_vector_type(4))) float f32x4;

#define D_MODEL 512
#define SEQ 16384

// ---- ws layout (bytes); total 72,089,600 (known-safe) ----
#define PART_OFF 0u            // bf16 [1024][8][64 e][64 d] = 67,108,864
#define SUMS_OFF 67108864u     // f32  [1024][8][64]         = 2,097,152
#define CTX_OFF  69206016u     // f32  [16][64 d][64 e]      = 262,144
#define WTK_OFF  69468160u     // bf16 512x512 = 524,288
#define WTV_OFF  69992448u
#define WTQ_OFF  70516736u
#define MBIGT_OFF 71041024u    // bf16 [2][512][512] = 1,048,576
#define WS_NEEDED 72089600u

__device__ __forceinline__ float bf2f(u16 u) {
  union { unsigned int i; float f; } x; x.i = ((unsigned int)u) << 16; return x.f;
}
__device__ __forceinline__ u16 f2bf(float f) {
  union { float ff; unsigned int i; } x; x.ff = f;
  unsigned int r = x.i + 0x7fffu + ((x.i >> 16) & 1u);  // RNE
  return (u16)(r >> 16);
}
__device__ __forceinline__ unsigned int pk2(float lo, float hi) {
  union { __hip_bfloat162 h; unsigned int u; } x;
  x.h = __float22bfloat162_rn(float2{lo, hi});
  return x.u;
}
__device__ __forceinline__ bf16x8 ldsrd(const u16* base, int row, int rowbytes,
                                        int kbyte, int mask) {
  return *(const bf16x8*)((const char*)base + row * rowbytes + (kbyte ^ ((row & mask) << 4)));
}

// ---------------- transpose+convert all three W -> WT bf16 ------------------
__launch_bounds__(256)
__global__ void wcvt_kernel(const float* __restrict__ Wk, const float* __restrict__ Wv,
                            const float* __restrict__ Wq, u16* __restrict__ WTk,
                            u16* __restrict__ WTv, u16* __restrict__ WTq) {
  const float* in = blockIdx.z == 0 ? Wk : (blockIdx.z == 1 ? Wv : Wq);
  u16* out = blockIdx.z == 0 ? WTk : (blockIdx.z == 1 ? WTv : WTq);
  __shared__ float S[64][65];
  const int t = threadIdx.x;
  const int i0 = blockIdx.y << 6, j0 = blockIdx.x << 6;
#pragma unroll
  for (int ii = 0; ii < 4; ++ii) {
    const int idx = t + ii * 256;
    const int r = idx >> 4, c4 = (idx & 15) << 2;
    const float4 v = *(const float4*)(in + (i0 + r) * D_MODEL + j0 + c4);
    S[r][c4] = v.x; S[r][c4 + 1] = v.y; S[r][c4 + 2] = v.z; S[r][c4 + 3] = v.w;
  }
  __syncthreads();
#pragma unroll
  for (int ii = 0; ii < 4; ++ii) {
    const int idx = t + ii * 256;
    const int c = idx >> 4, r4 = (idx & 15) << 2;
    ushort4 o;
    o.x = f2bf(S[r4][c]); o.y = f2bf(S[r4 + 1][c]);
    o.z = f2bf(S[r4 + 2][c]); o.w = f2bf(S[r4 + 3][c]);
    *(ushort4*)(out + (j0 + c) * D_MODEL + i0 + r4) = o;
  }
}

// ---------------- phase 1: K∥V pipeline + per-head E^T V --------------------
__launch_bounds__(512, 4)
__global__ void phase1_kernel(const float* __restrict__ key, const float* __restrict__ value,
                              const u16* __restrict__ WTk, const u16* __restrict__ WTv,
                              const float* __restrict__ bkp, const float* __restrict__ bvp,
                              u16* __restrict__ part, float* __restrict__ sums) {
  __shared__ __align__(16) u16 smem[40960];  // 80KB
  u16* SLK = smem;                  // [2][2048] K slices (32n x 64k bf16)
  u16* SLV = smem + 4096;           // [2][2048] V slices
  const int t = threadIdx.x;
  const int lane = t & 63, w = t >> 6;
  const int g = lane >> 4, lc = lane & 15;
  const int chunk = blockIdx.x;
  const int n0 = chunk * 32;
  const int h = w;                  // 8 waves = 8 heads
  u16* ETw = smem + 8192 + w * 2048;    // [64 d][32 n], rows 64B, swz mask 3
  u16* VTw = smem + 24576 + w * 2048;   // [64 e][32 n]
  const u16* WThk = WTk + (size_t)h * 64 * D_MODEL;
  const u16* WThv = WTv + (size_t)h * 64 * D_MODEL;

  const int srow = t >> 4;              // 0..31
  const int scol = (t & 15) << 2;       // f32 col
  const int sbyte = srow * 128 + (((t & 15) << 3) ^ ((srow & 7) << 4));
  const float* kbase = key + (size_t)(n0 + srow) * D_MODEL + scol;
  const float* vbase = value + (size_t)(n0 + srow) * D_MODEL + scol;

  float4 ldk[2], ldv[2];
  f32x4 ae[2][4], av[2][4];
#pragma unroll
  for (int m = 0; m < 2; ++m)
#pragma unroll
    for (int n = 0; n < 4; ++n) { ae[m][n] = (f32x4){0.f,0.f,0.f,0.f}; av[m][n] = (f32x4){0.f,0.f,0.f,0.f}; }

  // preamble: slices 0,1 in regs; slice 0 -> LDS buf0
  ldk[0] = *(const float4*)(kbase);      ldv[0] = *(const float4*)(vbase);
  ldk[1] = *(const float4*)(kbase + 64); ldv[1] = *(const float4*)(vbase + 64);
  *(uint2*)((char*)SLK + sbyte) = make_uint2(pk2(ldk[0].x, ldk[0].y), pk2(ldk[0].z, ldk[0].w));
  *(uint2*)((char*)SLV + sbyte) = make_uint2(pk2(ldv[0].x, ldv[0].y), pk2(ldv[0].z, ldv[0].w));
  __syncthreads();

#pragma unroll
  for (int ks = 0; ks < 8; ++ks) {
    if (ks + 2 < 8) {                    // dist-2 prefetch into freed reg set
      ldk[ks & 1] = *(const float4*)(kbase + (ks + 2) * 64);
      ldv[ks & 1] = *(const float4*)(vbase + (ks + 2) * 64);
    }
    if (ks + 1 < 8) {                    // write next slice to opposite buffer
      const int p = (ks + 1) & 1;
      *(uint2*)((char*)SLK + p * 4096 + sbyte) =
          make_uint2(pk2(ldk[p].x, ldk[p].y), pk2(ldk[p].z, ldk[p].w));
      *(uint2*)((char*)SLV + p * 4096 + sbyte) =
          make_uint2(pk2(ldv[p].x, ldv[p].y), pk2(ldv[p].z, ldv[p].w));
    }
    const u16* bK = SLK + (ks & 1) * 2048;
    const u16* bV = SLV + (ks & 1) * 2048;
#pragma unroll
    for (int kk = 0; kk < 2; ++kk) {
      {
        bf16x8 afk[2], bfk[4];
#pragma unroll
        for (int mf = 0; mf < 2; ++mf) afk[mf] = ldsrd(bK, mf * 16 + lc, 128, kk * 64 + g * 16, 7);
#pragma unroll
        for (int nf = 0; nf < 4; ++nf)
          bfk[nf] = *(const bf16x8*)(WThk + (size_t)(nf * 16 + lc) * D_MODEL + ks * 64 + kk * 32 + g * 8);
#pragma unroll
        for (int mf = 0; mf < 2; ++mf)
#pragma unroll
          for (int nf = 0; nf < 4; ++nf)
            ae[mf][nf] = __builtin_amdgcn_mfma_f32_16x16x32_bf16(afk[mf], bfk[nf], ae[mf][nf], 0, 0, 0);
      }
      {
        bf16x8 afv[2], bfv[4];
#pragma unroll
        for (int mf = 0; mf < 2; ++mf) afv[mf] = ldsrd(bV, mf * 16 + lc, 128, kk * 64 + g * 16, 7);
#pragma unroll
        for (int nf = 0; nf < 4; ++nf)
          bfv[nf] = *(const bf16x8*)(WThv + (size_t)(nf * 16 + lc) * D_MODEL + ks * 64 + kk * 32 + g * 8);
#pragma unroll
        for (int mf = 0; mf < 2; ++mf)
#pragma unroll
          for (int nf = 0; nf < 4; ++nf)
            av[mf][nf] = __builtin_amdgcn_mfma_f32_16x16x32_bf16(afv[mf], bfv[nf], av[mf][nf], 0, 0, 0);
      }
    }
    __syncthreads();
  }

  // ---- E epilogue: exp, colsum, E^T -> ETw (wave-private) ----
#pragma unroll
  for (int nf = 0; nf < 4; ++nf) {
    const float bb = bkp[h * 64 + nf * 16 + lc];
    float s = 0.f;
#pragma unroll
    for (int mf = 0; mf < 2; ++mf)
#pragma unroll
      for (int r = 0; r < 4; ++r) {
        const float v = __expf(ae[mf][nf][r] + bb);
        ae[mf][nf][r] = v; s += v;
      }
    s += __shfl_xor(s, 16); s += __shfl_xor(s, 32);
    const int d = nf * 16 + lc;
    if (g == 0) sums[(size_t)(chunk * 8 + h) * 64 + d] = s;
#pragma unroll
    for (int mf = 0; mf < 2; ++mf) {
      const uint2 pw = make_uint2(pk2(ae[mf][nf][0], ae[mf][nf][1]),
                                  pk2(ae[mf][nf][2], ae[mf][nf][3]));
      *(uint2*)((char*)ETw + d * 64 + ((mf * 32 + g * 8) ^ ((d & 3) << 4))) = pw;
    }
  }
  // ---- V epilogue: bias, V^T -> VTw ----
#pragma unroll
  for (int nf = 0; nf < 4; ++nf) {
    const float bb = bvp[h * 64 + nf * 16 + lc];
    const int e = nf * 16 + lc;
#pragma unroll
    for (int mf = 0; mf < 2; ++mf) {
      const uint2 pw = make_uint2(pk2(av[mf][nf][0] + bb, av[mf][nf][1] + bb),
                                  pk2(av[mf][nf][2] + bb, av[mf][nf][3] + bb));
      *(uint2*)((char*)VTw + e * 64 + ((mf * 32 + g * 8) ^ ((e & 3) << 4))) = pw;
    }
  }
  // ---- partial[e][d] = (E^T V)^T-store (k = 32 rows), wave-private ----
  {
    bf16x8 paf[4], pbf[4];
#pragma unroll
    for (int dm = 0; dm < 4; ++dm) paf[dm] = ldsrd(ETw, dm * 16 + lc, 64, g * 16, 3);
#pragma unroll
    for (int em = 0; em < 4; ++em) pbf[em] = ldsrd(VTw, em * 16 + lc, 64, g * 16, 3);
    u16* pp = part + (size_t)(chunk * 8 + h) * 4096;
#pragma unroll
    for (int dm = 0; dm < 4; ++dm)
#pragma unroll
      for (int em = 0; em < 4; ++em) {
        f32x4 pc = __builtin_amdgcn_mfma_f32_16x16x32_bf16(paf[dm], pbf[em],
                     (f32x4){0.f, 0.f, 0.f, 0.f}, 0, 0, 0);
        ushort4 o;
        o.x = f2bf(pc[0]); o.y = f2bf(pc[1]); o.z = f2bf(pc[2]); o.w = f2bf(pc[3]);
        *(ushort4*)(pp + (em * 16 + lc) * 64 + dm * 16 + g * 4) = o;  // [e][d]
      }
  }
}

// ---------------- phase 2: reduce partials -> ctx[d][e] ---------------------
// 64x64 tile = 1024 ushort4 quads; block (x,bh) covers quads q = x*64 .. x*64+63.
// MUST be launched with gridDim.x == 16 (q in 0..1023).
__launch_bounds__(256)
__global__ void reduce_kernel(const u16* __restrict__ part, const float* __restrict__ sums,
                              float* __restrict__ ctx) {
  __shared__ float pbuf[4][64][4];   // [seg][quad][j]
  __shared__ float sbuf[4][64];      // [seg][d]
  const int x = blockIdx.x, bh = blockIdx.y;
  const int b = bh >> 3, h = bh & 7;
  const int t = threadIdx.x, seg = t >> 6, ql = t & 63;
  const int q = x * 64 + ql, e = q >> 4, d0 = (q & 15) << 2;
  float a0 = 0.f, a1 = 0.f, a2 = 0.f, a3 = 0.f, s = 0.f;
  for (int cc = seg * 128; cc < seg * 128 + 128; ++cc) {
    const size_t gbh = (size_t)(b * 512 + cc) * 8 + h;
    const ushort4 u = *(const ushort4*)(part + (gbh << 12) + e * 64 + d0);
    a0 += bf2f(u.x); a1 += bf2f(u.y); a2 += bf2f(u.z); a3 += bf2f(u.w);
    s += sums[gbh * 64 + ql];
  }
  pbuf[seg][ql][0] = a0; pbuf[seg][ql][1] = a1;
  pbuf[seg][ql][2] = a2; pbuf[seg][ql][3] = a3;
  sbuf[seg][ql] = s;
  __syncthreads();
  if (t < 64) {
    const int q2 = x * 64 + t, e2 = q2 >> 4, d02 = (q2 & 15) << 2;
#pragma unroll
    for (int j = 0; j < 4; ++j) {
      const float num = pbuf[0][t][j] + pbuf[1][t][j] + pbuf[2][t][j] + pbuf[3][t][j];
      const int d = d02 + j;
      const float den = sbuf[0][d] + sbuf[1][d] + sbuf[2][d] + sbuf[3][d];
      ctx[(size_t)bh * 4096 + d * 64 + e2] = num / den;
    }
  }
}

// -------- MbigT[b][c][h*64+d] (bf16) = sum_e ctx[b,h,d,e] * Wo[h*64+e][c] ---
__launch_bounds__(256)
__global__ void mbigT_kernel(const float* __restrict__ ctx, const float* __restrict__ Wo,
                             u16* __restrict__ MbigT) {
  __shared__ float Clds[64][65];
  __shared__ float Wlds2[64][64];
  const int t = threadIdx.x;
  const int tx = t & 15, ty = t >> 4;
  const int cc = blockIdx.x;
  const int bh = blockIdx.y;
  const int b = bh >> 3, h = bh & 7;
  const float* ch = ctx + bh * 4096;
  for (int i4 = t; i4 < 1024; i4 += 256) {
    const int r = i4 >> 4, c = (i4 & 15) << 2;
    const float4 v = *(const float4*)(ch + (r << 6) + c);
    Clds[r][c] = v.x; Clds[r][c + 1] = v.y; Clds[r][c + 2] = v.z; Clds[r][c + 3] = v.w;
    const float4 wv = *(const float4*)(Wo + (h * 64 + r) * D_MODEL + cc * 64 + c);
    Wlds2[r][c] = wv.x; Wlds2[r][c + 1] = wv.y; Wlds2[r][c + 2] = wv.z; Wlds2[r][c + 3] = wv.w;
  }
  __syncthreads();
  float acc[4][4] = {};
#pragma unroll 8
  for (int k = 0; k < 64; ++k) {
    float a[4], wv[4];
#pragma unroll
    for (int i = 0; i < 4; ++i) a[i] = Clds[(ty << 2) + i][k];
#pragma unroll
    for (int j = 0; j < 4; ++j) wv[j] = Wlds2[k][(tx << 2) + j];
#pragma unroll
    for (int i = 0; i < 4; ++i)
#pragma unroll
      for (int j = 0; j < 4; ++j) acc[i][j] = fmaf(a[i], wv[j], acc[i][j]);
  }
  u16* mp = MbigT + b * D_MODEL * D_MODEL;
#pragma unroll
  for (int i = 0; i < 4; ++i)
#pragma unroll
    for (int j = 0; j < 4; ++j)
      mp[(cc * 64 + (tx << 2) + j) * D_MODEL + h * 64 + (ty << 2) + i] = f2bf(acc[i][j]);
}

// ---------------- phase 3: Q pipeline + softmax + out-GEMM ------------------
__launch_bounds__(512, 4)
__global__ void phase3_kernel(const float* __restrict__ query, const u16* __restrict__ WTq,
                              const float* __restrict__ bqp, const u16* __restrict__ MbigT,
                              const float* __restrict__ bop, float* __restrict__ out) {
  __shared__ __align__(16) u16 smem[20480];  // 40KB
  u16* SL = smem;          // [2][2048] Q slices
  u16* P  = smem + 4096;   // [32 n][512 d], rows 1024B, swz mask 7
  const int t = threadIdx.x;
  const int lane = t & 63, w = t >> 6;
  const int g = lane >> 4, lc = lane & 15;
  const int chunk = blockIdx.x;
  const int n0 = chunk * 32;
  const int b = chunk >> 9;
  const int c0 = w * 64;
  const int srow = t >> 4;
  const int scol = (t & 15) << 2;
  const int sbyte = srow * 128 + (((t & 15) << 3) ^ ((srow & 7) << 4));
  const float* qbase = query + (size_t)(n0 + srow) * D_MODEL + scol;

  float4 lq[2];
  f32x4 acc[4][2];
#pragma unroll
  for (int m = 0; m < 4; ++m)
#pragma unroll
    for (int n = 0; n < 2; ++n) acc[m][n] = (f32x4){0.f, 0.f, 0.f, 0.f};

  lq[0] = *(const float4*)(qbase);
  lq[1] = *(const float4*)(qbase + 64);
  *(uint2*)((char*)SL + sbyte) = make_uint2(pk2(lq[0].x, lq[0].y), pk2(lq[0].z, lq[0].w));
  __syncthreads();

#pragma unroll
  for (int ks = 0; ks < 8; ++ks) {
    if (ks + 2 < 8) lq[ks & 1] = *(const float4*)(qbase + (ks + 2) * 64);
    if (ks + 1 < 8) {
      const int p = (ks + 1) & 1;
      *(uint2*)((char*)SL + p * 4096 + sbyte) =
          make_uint2(pk2(lq[p].x, lq[p].y), pk2(lq[p].z, lq[p].w));
    }
    const u16* S = SL + (ks & 1) * 2048;
#pragma unroll
    for (int kk = 0; kk < 2; ++kk) {
      bf16x8 af[4], bfr[2];
#pragma unroll
      for (int mf = 0; mf < 4; ++mf)
        af[mf] = *(const bf16x8*)(WTq + (size_t)(c0 + mf * 16 + lc) * D_MODEL + ks * 64 + kk * 32 + g * 8);
#pragma unroll
      for (int nf = 0; nf < 2; ++nf) bfr[nf] = ldsrd(S, nf * 16 + lc, 128, kk * 64 + g * 16, 7);
#pragma unroll
      for (int mf = 0; mf < 4; ++mf)
#pragma unroll
        for (int nf = 0; nf < 2; ++nf)
          acc[mf][nf] = __builtin_amdgcn_mfma_f32_16x16x32_bf16(af[mf], bfr[nf], acc[mf][nf], 0, 0, 0);
    }
    __syncthreads();
  }
  // ---- softmax over d (per n), *1/8, bf16 -> P ----
  {
    float bqv[4][4];
#pragma unroll
    for (int m = 0; m < 4; ++m)
#pragma unroll
      for (int r = 0; r < 4; ++r) bqv[m][r] = bqp[c0 + m * 16 + g * 4 + r];
#pragma unroll
    for (int nf = 0; nf < 2; ++nf) {
      float mx = -3.0e38f;
#pragma unroll
      for (int m = 0; m < 4; ++m)
#pragma unroll
        for (int r = 0; r < 4; ++r) {
          const float v = acc[m][nf][r] + bqv[m][r];
          acc[m][nf][r] = v; mx = fmaxf(mx, v);
        }
      mx = fmaxf(mx, __shfl_xor(mx, 16)); mx = fmaxf(mx, __shfl_xor(mx, 32));
      float s = 0.f;
#pragma unroll
      for (int m = 0; m < 4; ++m)
#pragma unroll
        for (int r = 0; r < 4; ++r) {
          const float e = __expf(acc[m][nf][r] - mx);
          acc[m][nf][r] = e; s += e;
        }
      s += __shfl_xor(s, 16); s += __shfl_xor(s, 32);
      const float f = 0.125f / s;
      const int n = nf * 16 + lc;
#pragma unroll
      for (int m = 0; m < 4; ++m) {
        const uint2 pw = make_uint2(pk2(acc[m][nf][0] * f, acc[m][nf][1] * f),
                                    pk2(acc[m][nf][2] * f, acc[m][nf][3] * f));
        *(uint2*)((char*)P + n * 1024 + ((w * 128 + m * 32 + g * 8) ^ ((n & 7) << 4))) = pw;
      }
    }
  }
  __syncthreads();
  // ---- out^T = MbigT[b] @ P^T ----
  f32x4 oc[4][2];
#pragma unroll
  for (int m = 0; m < 4; ++m)
#pragma unroll
    for (int n = 0; n < 2; ++n) oc[m][n] = (f32x4){0.f, 0.f, 0.f, 0.f};
  const u16* MT = MbigT + (size_t)b * D_MODEL * D_MODEL;
#pragma unroll 2
  for (int ks = 0; ks < 16; ++ks) {
    bf16x8 af[4], bfr[2];
#pragma unroll
    for (int mf = 0; mf < 4; ++mf)
      af[mf] = *(const bf16x8*)(MT + (size_t)(c0 + mf * 16 + lc) * D_MODEL + ks * 32 + g * 8);
#pragma unroll
    for (int nf = 0; nf < 2; ++nf) bfr[nf] = ldsrd(P, nf * 16 + lc, 1024, ks * 64 + g * 16, 7);
#pragma unroll
    for (int mf = 0; mf < 4; ++mf)
#pragma unroll
      for (int nf = 0; nf < 2; ++nf)
        oc[mf][nf] = __builtin_amdgcn_mfma_f32_16x16x32_bf16(af[mf], bfr[nf], oc[mf][nf], 0, 0, 0);
  }
  {
    float bov[4][4];
#pragma unroll
    for (int m = 0; m < 4; ++m)
#pragma unroll
      for (int r = 0; r < 4; ++r) bov[m][r] = bop[c0 + m * 16 + g * 4 + r];
#pragma unroll
    for (int mf = 0; mf < 4; ++mf)
#pragma unroll
      for (int nf = 0; nf < 2; ++nf) {
        float4 o;
        o.x = oc[mf][nf][0] + bov[mf][0]; o.y = oc[mf][nf][1] + bov[mf][1];
        o.z = oc[mf][nf][2] + bov[mf][2]; o.w = oc[mf][nf][3] + bov[mf][3];
        *(float4*)(out + (size_t)(n0 + nf * 16 + lc) * D_MODEL + c0 + mf * 16 + g * 4) = o;
      }
  }
}

__global__ void sentinel_kernel(float* out) { out[0] = 1.0e9f; }

extern "C" void kernel_launch(void* const* d_in, const int* in_sizes, int n_in,
                              void* d_out, int out_size, void* d_ws, size_t ws_size,
                              hipStream_t stream) {
  const float* query = (const float*)d_in[0];
  const float* key   = (const float*)d_in[1];
  const float* value = (const float*)d_in[2];
  const float* Wq = (const float*)d_in[3];
  const float* bq = (const float*)d_in[4];
  const float* Wk = (const float*)d_in[5];
  const float* bk = (const float*)d_in[6];
  const float* Wv = (const float*)d_in[7];
  const float* bv = (const float*)d_in[8];
  const float* Wo = (const float*)d_in[9];
  const float* bo = (const float*)d_in[10];
  float* out = (float*)d_out;
  char* ws = (char*)d_ws;

  if (ws_size < (size_t)WS_NEEDED) {
    sentinel_kernel<<<1, 1, 0, stream>>>(out);
    return;
  }

  u16* part   = (u16*)(ws + PART_OFF);
  float* sums = (float*)(ws + SUMS_OFF);
  float* ctx  = (float*)(ws + CTX_OFF);
  u16* WTk    = (u16*)(ws + WTK_OFF);
  u16* WTv    = (u16*)(ws + WTV_OFF);
  u16* WTq    = (u16*)(ws + WTQ_OFF);
  u16* MbigT  = (u16*)(ws + MBIGT_OFF);

  const dim3 blk256(256);
  wcvt_kernel<<<dim3(8, 8, 3), blk256, 0, stream>>>(Wk, Wv, Wq, WTk, WTv, WTq);
  phase1_kernel<<<1024, 512, 0, stream>>>(key, value, WTk, WTv, bk, bv, part, sums);
  reduce_kernel<<<dim3(16, 16), blk256, 0, stream>>>(part, sums, ctx);  // FIX: was (4,16)
  mbigT_kernel<<<dim3(8, 16), blk256, 0, stream>>>(ctx, Wo, MbigT);
  phase3_kernel<<<1024, 512, 0, stream>>>(query, WTq, bq, MbigT, bo, out);
}

// Round 7
// 306.561 us; speedup vs baseline: 1.3855x; 1.0379x over previous
//
#include <hip/hip_runtime.h>
#include <hip/hip_bf16.h>

// Linear attention (Shen 2018), B=2, N=16384, D=512, H=8, DK=64.
// Round 7: phase1 rewritten with register-resident B-panels (block = 2 heads
// x 4 col-quarter waves, loops 8 chunks; WT frags loaded once per block) and
// lgkmcnt-only barriers (no vmcnt drain). phase3 = R6 logic + lgkm barriers.

using u16 = unsigned short;
typedef __attribute__((ext_vector_type(8))) short bf16x8;
typedef __attribute__((ext_vector_type(4))) float f32x4;

#define D_MODEL 512
#define SEQ 16384

// ---- ws layout (bytes); total 72,089,600 (known-safe) ----
#define PART_OFF 0u            // bf16 [16 bh][512 cloc][64 e][64 d] = 67,108,864
#define SUMS_OFF 67108864u     // f32  [16 bh][512 cloc][64 d]      = 2,097,152
#define CTX_OFF  69206016u     // f32  [16][64 d][64 e]             = 262,144
#define WTK_OFF  69468160u     // bf16 512x512 = 524,288
#define WTV_OFF  69992448u
#define WTQ_OFF  70516736u
#define MBIGT_OFF 71041024u    // bf16 [2][512][512] = 1,048,576
#define WS_NEEDED 72089600u

__device__ __forceinline__ float bf2f(u16 u) {
  union { unsigned int i; float f; } x; x.i = ((unsigned int)u) << 16; return x.f;
}
__device__ __forceinline__ u16 f2bf(float f) {
  union { float ff; unsigned int i; } x; x.ff = f;
  unsigned int r = x.i + 0x7fffu + ((x.i >> 16) & 1u);  // RNE
  return (u16)(r >> 16);
}
__device__ __forceinline__ unsigned int pk2(float lo, float hi) {
  union { __hip_bfloat162 h; unsigned int u; } x;
  x.h = __float22bfloat162_rn(float2{lo, hi});
  return x.u;
}
__device__ __forceinline__ bf16x8 ldsrd(const u16* base, int row, int rowbytes,
                                        int kbyte, int mask) {
  return *(const bf16x8*)((const char*)base + row * rowbytes + (kbyte ^ ((row & mask) << 4)));
}
// barrier that does NOT drain vmcnt: LDS ordering only. Safe because at every
// barrier the only in-flight vmem ops are register-destined loads (wave
// private) or fire-and-forget global stores.
__device__ __forceinline__ void bar_lgkm() {
  asm volatile("s_waitcnt lgkmcnt(0)" ::: "memory");
  __builtin_amdgcn_sched_barrier(0);
  __builtin_amdgcn_s_barrier();
  __builtin_amdgcn_sched_barrier(0);
}

// ---------------- transpose+convert all three W -> WT bf16 ------------------
__launch_bounds__(256)
__global__ void wcvt_kernel(const float* __restrict__ Wk, const float* __restrict__ Wv,
                            const float* __restrict__ Wq, u16* __restrict__ WTk,
                            u16* __restrict__ WTv, u16* __restrict__ WTq) {
  const float* in = blockIdx.z == 0 ? Wk : (blockIdx.z == 1 ? Wv : Wq);
  u16* out = blockIdx.z == 0 ? WTk : (blockIdx.z == 1 ? WTv : WTq);
  __shared__ float S[64][65];
  const int t = threadIdx.x;
  const int i0 = blockIdx.y << 6, j0 = blockIdx.x << 6;
#pragma unroll
  for (int ii = 0; ii < 4; ++ii) {
    const int idx = t + ii * 256;
    const int r = idx >> 4, c4 = (idx & 15) << 2;
    const float4 v = *(const float4*)(in + (i0 + r) * D_MODEL + j0 + c4);
    S[r][c4] = v.x; S[r][c4 + 1] = v.y; S[r][c4 + 2] = v.z; S[r][c4 + 3] = v.w;
  }
  __syncthreads();
#pragma unroll
  for (int ii = 0; ii < 4; ++ii) {
    const int idx = t + ii * 256;
    const int c = idx >> 4, r4 = (idx & 15) << 2;
    ushort4 o;
    o.x = f2bf(S[r4][c]); o.y = f2bf(S[r4 + 1][c]);
    o.z = f2bf(S[r4 + 2][c]); o.w = f2bf(S[r4 + 3][c]);
    *(ushort4*)(out + (j0 + c) * D_MODEL + i0 + r4) = o;
  }
}

// ---------------- phase 1: chunk-looping, register-B K/V proj + E^T V -------
// grid (4, 128): hp = blockIdx.x (heads 2hp,2hp+1), 8 chunks of 32 rows each.
// wave w: head h = 2hp + (w>>2), col-quarter cq = w&3 (16 cols).
__launch_bounds__(512, 2)
__global__ void phase1_kernel(const float* __restrict__ key, const float* __restrict__ value,
                              const u16* __restrict__ WTk, const u16* __restrict__ WTv,
                              const float* __restrict__ bkp, const float* __restrict__ bvp,
                              u16* __restrict__ part, float* __restrict__ sums) {
  __shared__ __align__(16) u16 smem[40960];  // 80KB
  u16* KA = smem;            // [32 n][512 k] bf16, rows 1024B, swz mask 7
  u16* VA = smem + 16384;
  u16* ET = smem + 32768;    // [2 hloc][64 d][32 n], rows 64B, swz mask 3
  u16* VT = smem + 36864;
  const int t = threadIdx.x;
  const int lane = t & 63, w = t >> 6;
  const int g = lane >> 4, lc = lane & 15;
  const int hp = blockIdx.x;
  const int hloc = w >> 2;
  const int h = hp * 2 + hloc;
  const int cq = w & 3;
  const int c0row = h * 64 + cq * 16;   // WT row (= projection output col)
  u16* ETh = ET + hloc * 2048;
  u16* VTh = VT + hloc * 2048;

  // ---- B-fragments for this wave's 16 cols, full K: loaded ONCE ----
  bf16x8 bK[16], bV[16];
#pragma unroll
  for (int ks = 0; ks < 16; ++ks) {
    bK[ks] = *(const bf16x8*)(WTk + (size_t)(c0row + lc) * D_MODEL + ks * 32 + g * 8);
    bV[ks] = *(const bf16x8*)(WTv + (size_t)(c0row + lc) * D_MODEL + ks * 32 + g * 8);
  }
  const float bbk = bkp[c0row + lc];
  const float bbv = bvp[c0row + lc];

  const int srow = t >> 4, sc8 = t & 15;
  const int dl = cq * 16 + lc;  // within-head output col

  for (int ci = 0; ci < 8; ++ci) {
    const int chunk = (int)blockIdx.y * 8 + ci;
    const int n0 = chunk * 32;
    const int cloc = chunk & 511;
    const size_t bh512 = (size_t)((chunk >> 9) * 8 + h) * 512 + cloc;

    // ---- stage K,V chunk (coalesced f32 loads -> bf16 swizzled LDS) ----
    {
      const float* kp = key + (size_t)(n0 + srow) * D_MODEL + sc8 * 4;
      const float* vp = value + (size_t)(n0 + srow) * D_MODEL + sc8 * 4;
      float4 lk[8], lv[8];
#pragma unroll
      for (int j = 0; j < 8; ++j) lk[j] = *(const float4*)(kp + j * 64);
#pragma unroll
      for (int j = 0; j < 8; ++j) lv[j] = *(const float4*)(vp + j * 64);
#pragma unroll
      for (int j = 0; j < 8; ++j) {
        const int off = srow * 1024 + j * 128 + (((sc8) << 3) ^ ((srow & 7) << 4));
        *(uint2*)((char*)KA + off) = make_uint2(pk2(lk[j].x, lk[j].y), pk2(lk[j].z, lk[j].w));
        *(uint2*)((char*)VA + off) = make_uint2(pk2(lv[j].x, lv[j].y), pk2(lv[j].z, lv[j].w));
      }
    }
    bar_lgkm();

    // ---- K-GEMM and V-GEMM (A from LDS, B from regs; no barriers) ----
    f32x4 aeK[2], aeV[2];
#pragma unroll
    for (int m = 0; m < 2; ++m) { aeK[m] = (f32x4){0.f,0.f,0.f,0.f}; aeV[m] = (f32x4){0.f,0.f,0.f,0.f}; }
#pragma unroll
    for (int ks = 0; ks < 16; ++ks) {
      const int kb = ks * 64 + g * 16;
      bf16x8 ak0 = ldsrd(KA, lc, 1024, kb, 7);
      bf16x8 ak1 = ldsrd(KA, 16 + lc, 1024, kb, 7);
      aeK[0] = __builtin_amdgcn_mfma_f32_16x16x32_bf16(ak0, bK[ks], aeK[0], 0, 0, 0);
      aeK[1] = __builtin_amdgcn_mfma_f32_16x16x32_bf16(ak1, bK[ks], aeK[1], 0, 0, 0);
      bf16x8 av0 = ldsrd(VA, lc, 1024, kb, 7);
      bf16x8 av1 = ldsrd(VA, 16 + lc, 1024, kb, 7);
      aeV[0] = __builtin_amdgcn_mfma_f32_16x16x32_bf16(av0, bV[ks], aeV[0], 0, 0, 0);
      aeV[1] = __builtin_amdgcn_mfma_f32_16x16x32_bf16(av1, bV[ks], aeV[1], 0, 0, 0);
    }

    // ---- E epilogue: exp, colsum, E^T strip -> ETh (rows dl, per-wave) ----
    {
      float s = 0.f;
#pragma unroll
      for (int m = 0; m < 2; ++m)
#pragma unroll
        for (int r = 0; r < 4; ++r) {
          const float v = __expf(aeK[m][r] + bbk);
          aeK[m][r] = v; s += v;
        }
      s += __shfl_xor(s, 16); s += __shfl_xor(s, 32);
      if (g == 0) sums[bh512 * 64 + dl] = s;
#pragma unroll
      for (int m = 0; m < 2; ++m) {
        const uint2 pw = make_uint2(pk2(aeK[m][0], aeK[m][1]), pk2(aeK[m][2], aeK[m][3]));
        *(uint2*)((char*)ETh + dl * 64 + ((m * 32 + g * 8) ^ ((dl & 3) << 4))) = pw;
      }
    }
    // ---- V epilogue: bias, V^T strip -> VTh ----
#pragma unroll
    for (int m = 0; m < 2; ++m) {
      const uint2 pw = make_uint2(pk2(aeV[m][0] + bbv, aeV[m][1] + bbv),
                                  pk2(aeV[m][2] + bbv, aeV[m][3] + bbv));
      *(uint2*)((char*)VTh + dl * 64 + ((m * 32 + g * 8) ^ ((dl & 3) << 4))) = pw;
    }
    bar_lgkm();  // ET/VT visible to the head's 4 waves

    // ---- partial[e][d] strip: (E^T V) rows d = cq*16..+15, k = 32 rows ----
    {
      bf16x8 paf = ldsrd(ETh, cq * 16 + lc, 64, g * 16, 3);
      u16* pp = part + bh512 * 4096;
#pragma unroll
      for (int em = 0; em < 4; ++em) {
        bf16x8 pbf = ldsrd(VTh, em * 16 + lc, 64, g * 16, 3);
        f32x4 pc = __builtin_amdgcn_mfma_f32_16x16x32_bf16(paf, pbf,
                     (f32x4){0.f, 0.f, 0.f, 0.f}, 0, 0, 0);
        ushort4 o;
        o.x = f2bf(pc[0]); o.y = f2bf(pc[1]); o.z = f2bf(pc[2]); o.w = f2bf(pc[3]);
        *(ushort4*)(pp + (em * 16 + lc) * 64 + cq * 16 + g * 4) = o;
      }
    }
    bar_lgkm();  // ET/VT + KA/VA reads done before next chunk overwrites
  }
}

// ---------------- phase 2: reduce partials -> ctx[d][e] ---------------------
// part is bh-contiguous: base = bh*512*4096. gridDim MUST be (16,16).
__launch_bounds__(256)
__global__ void reduce_kernel(const u16* __restrict__ part, const float* __restrict__ sums,
                              float* __restrict__ ctx) {
  __shared__ float pbuf[4][64][4];
  __shared__ float sbuf[4][64];
  const int x = blockIdx.x, bh = blockIdx.y;
  const int t = threadIdx.x, seg = t >> 6, ql = t & 63;
  const int q = x * 64 + ql, e = q >> 4, d0 = (q & 15) << 2;
  const u16* pbase = part + (size_t)bh * 512 * 4096;
  const float* sbase = sums + (size_t)bh * 512 * 64;
  float a0 = 0.f, a1 = 0.f, a2 = 0.f, a3 = 0.f, s = 0.f;
  for (int cc = seg * 128; cc < seg * 128 + 128; ++cc) {
    const ushort4 u = *(const ushort4*)(pbase + cc * 4096 + e * 64 + d0);
    a0 += bf2f(u.x); a1 += bf2f(u.y); a2 += bf2f(u.z); a3 += bf2f(u.w);
    s += sbase[cc * 64 + ql];
  }
  pbuf[seg][ql][0] = a0; pbuf[seg][ql][1] = a1;
  pbuf[seg][ql][2] = a2; pbuf[seg][ql][3] = a3;
  sbuf[seg][ql] = s;
  __syncthreads();
  if (t < 64) {
    const int q2 = x * 64 + t, e2 = q2 >> 4, d02 = (q2 & 15) << 2;
#pragma unroll
    for (int j = 0; j < 4; ++j) {
      const float num = pbuf[0][t][j] + pbuf[1][t][j] + pbuf[2][t][j] + pbuf[3][t][j];
      const int d = d02 + j;
      const float den = sbuf[0][d] + sbuf[1][d] + sbuf[2][d] + sbuf[3][d];
      ctx[(size_t)bh * 4096 + d * 64 + e2] = num / den;
    }
  }
}

// -------- MbigT[b][c][h*64+d] (bf16) = sum_e ctx[b,h,d,e] * Wo[h*64+e][c] ---
__launch_bounds__(256)
__global__ void mbigT_kernel(const float* __restrict__ ctx, const float* __restrict__ Wo,
                             u16* __restrict__ MbigT) {
  __shared__ float Clds[64][65];
  __shared__ float Wlds2[64][64];
  const int t = threadIdx.x;
  const int tx = t & 15, ty = t >> 4;
  const int cc = blockIdx.x;
  const int bh = blockIdx.y;
  const int b = bh >> 3, h = bh & 7;
  const float* ch = ctx + bh * 4096;
  for (int i4 = t; i4 < 1024; i4 += 256) {
    const int r = i4 >> 4, c = (i4 & 15) << 2;
    const float4 v = *(const float4*)(ch + (r << 6) + c);
    Clds[r][c] = v.x; Clds[r][c + 1] = v.y; Clds[r][c + 2] = v.z; Clds[r][c + 3] = v.w;
    const float4 wv = *(const float4*)(Wo + (h * 64 + r) * D_MODEL + cc * 64 + c);
    Wlds2[r][c] = wv.x; Wlds2[r][c + 1] = wv.y; Wlds2[r][c + 2] = wv.z; Wlds2[r][c + 3] = wv.w;
  }
  __syncthreads();
  float acc[4][4] = {};
#pragma unroll 8
  for (int k = 0; k < 64; ++k) {
    float a[4], wv[4];
#pragma unroll
    for (int i = 0; i < 4; ++i) a[i] = Clds[(ty << 2) + i][k];
#pragma unroll
    for (int j = 0; j < 4; ++j) wv[j] = Wlds2[k][(tx << 2) + j];
#pragma unroll
    for (int i = 0; i < 4; ++i)
#pragma unroll
      for (int j = 0; j < 4; ++j) acc[i][j] = fmaf(a[i], wv[j], acc[i][j]);
  }
  u16* mp = MbigT + b * D_MODEL * D_MODEL;
#pragma unroll
  for (int i = 0; i < 4; ++i)
#pragma unroll
    for (int j = 0; j < 4; ++j)
      mp[(cc * 64 + (tx << 2) + j) * D_MODEL + h * 64 + (ty << 2) + i] = f2bf(acc[i][j]);
}

// ---------------- phase 3: Q pipeline + softmax + out-GEMM (R6 + lgkm bar) --
__launch_bounds__(512, 4)
__global__ void phase3_kernel(const float* __restrict__ query, const u16* __restrict__ WTq,
                              const float* __restrict__ bqp, const u16* __restrict__ MbigT,
                              const float* __restrict__ bop, float* __restrict__ out) {
  __shared__ __align__(16) u16 smem[20480];  // 40KB
  u16* SL = smem;          // [2][2048] Q slices
  u16* P  = smem + 4096;   // [32 n][512 d], rows 1024B, swz mask 7
  const int t = threadIdx.x;
  const int lane = t & 63, w = t >> 6;
  const int g = lane >> 4, lc = lane & 15;
  const int chunk = blockIdx.x;
  const int n0 = chunk * 32;
  const int b = chunk >> 9;
  const int c0 = w * 64;
  const int srow = t >> 4;
  const int scol = (t & 15) << 2;
  const int sbyte = srow * 128 + (((t & 15) << 3) ^ ((srow & 7) << 4));
  const float* qbase = query + (size_t)(n0 + srow) * D_MODEL + scol;

  float4 lq[2];
  f32x4 acc[4][2];
#pragma unroll
  for (int m = 0; m < 4; ++m)
#pragma unroll
    for (int n = 0; n < 2; ++n) acc[m][n] = (f32x4){0.f, 0.f, 0.f, 0.f};

  lq[0] = *(const float4*)(qbase);
  lq[1] = *(const float4*)(qbase + 64);
  *(uint2*)((char*)SL + sbyte) = make_uint2(pk2(lq[0].x, lq[0].y), pk2(lq[0].z, lq[0].w));
  bar_lgkm();

#pragma unroll
  for (int ks = 0; ks < 8; ++ks) {
    if (ks + 2 < 8) lq[ks & 1] = *(const float4*)(qbase + (ks + 2) * 64);
    if (ks + 1 < 8) {
      const int p = (ks + 1) & 1;
      *(uint2*)((char*)SL + p * 4096 + sbyte) =
          make_uint2(pk2(lq[p].x, lq[p].y), pk2(lq[p].z, lq[p].w));
    }
    const u16* S = SL + (ks & 1) * 2048;
#pragma unroll
    for (int kk = 0; kk < 2; ++kk) {
      bf16x8 af[4], bfr[2];
#pragma unroll
      for (int mf = 0; mf < 4; ++mf)
        af[mf] = *(const bf16x8*)(WTq + (size_t)(c0 + mf * 16 + lc) * D_MODEL + ks * 64 + kk * 32 + g * 8);
#pragma unroll
      for (int nf = 0; nf < 2; ++nf) bfr[nf] = ldsrd(S, nf * 16 + lc, 128, kk * 64 + g * 16, 7);
#pragma unroll
      for (int mf = 0; mf < 4; ++mf)
#pragma unroll
        for (int nf = 0; nf < 2; ++nf)
          acc[mf][nf] = __builtin_amdgcn_mfma_f32_16x16x32_bf16(af[mf], bfr[nf], acc[mf][nf], 0, 0, 0);
    }
    bar_lgkm();
  }
  // ---- softmax over d (per n), *1/8, bf16 -> P ----
  {
    float bqv[4][4];
#pragma unroll
    for (int m = 0; m < 4; ++m)
#pragma unroll
      for (int r = 0; r < 4; ++r) bqv[m][r] = bqp[c0 + m * 16 + g * 4 + r];
#pragma unroll
    for (int nf = 0; nf < 2; ++nf) {
      float mx = -3.0e38f;
#pragma unroll
      for (int m = 0; m < 4; ++m)
#pragma unroll
        for (int r = 0; r < 4; ++r) {
          const float v = acc[m][nf][r] + bqv[m][r];
          acc[m][nf][r] = v; mx = fmaxf(mx, v);
        }
      mx = fmaxf(mx, __shfl_xor(mx, 16)); mx = fmaxf(mx, __shfl_xor(mx, 32));
      float s = 0.f;
#pragma unroll
      for (int m = 0; m < 4; ++m)
#pragma unroll
        for (int r = 0; r < 4; ++r) {
          const float e = __expf(acc[m][nf][r] - mx);
          acc[m][nf][r] = e; s += e;
        }
      s += __shfl_xor(s, 16); s += __shfl_xor(s, 32);
      const float f = 0.125f / s;
      const int n = nf * 16 + lc;
#pragma unroll
      for (int m = 0; m < 4; ++m) {
        const uint2 pw = make_uint2(pk2(acc[m][nf][0] * f, acc[m][nf][1] * f),
                                    pk2(acc[m][nf][2] * f, acc[m][nf][3] * f));
        *(uint2*)((char*)P + n * 1024 + ((w * 128 + m * 32 + g * 8) ^ ((n & 7) << 4))) = pw;
      }
    }
  }
  bar_lgkm();
  // ---- out^T = MbigT[b] @ P^T ----
  f32x4 oc[4][2];
#pragma unroll
  for (int m = 0; m < 4; ++m)
#pragma unroll
    for (int n = 0; n < 2; ++n) oc[m][n] = (f32x4){0.f, 0.f, 0.f, 0.f};
  const u16* MT = MbigT + (size_t)b * D_MODEL * D_MODEL;
#pragma unroll 2
  for (int ks = 0; ks < 16; ++ks) {
    bf16x8 af[4], bfr[2];
#pragma unroll
    for (int mf = 0; mf < 4; ++mf)
      af[mf] = *(const bf16x8*)(MT + (size_t)(c0 + mf * 16 + lc) * D_MODEL + ks * 32 + g * 8);
#pragma unroll
    for (int nf = 0; nf < 2; ++nf) bfr[nf] = ldsrd(P, nf * 16 + lc, 1024, ks * 64 + g * 16, 7);
#pragma unroll
    for (int mf = 0; mf < 4; ++mf)
#pragma unroll
      for (int nf = 0; nf < 2; ++nf)
        oc[mf][nf] = __builtin_amdgcn_mfma_f32_16x16x32_bf16(af[mf], bfr[nf], oc[mf][nf], 0, 0, 0);
  }
  {
    float bov[4][4];
#pragma unroll
    for (int m = 0; m < 4; ++m)
#pragma unroll
      for (int r = 0; r < 4; ++r) bov[m][r] = bop[c0 + m * 16 + g * 4 + r];
#pragma unroll
    for (int mf = 0; mf < 4; ++mf)
#pragma unroll
      for (int nf = 0; nf < 2; ++nf) {
        float4 o;
        o.x = oc[mf][nf][0] + bov[mf][0]; o.y = oc[mf][nf][1] + bov[mf][1];
        o.z = oc[mf][nf][2] + bov[mf][2]; o.w = oc[mf][nf][3] + bov[mf][3];
        *(float4*)(out + (size_t)(n0 + nf * 16 + lc) * D_MODEL + c0 + mf * 16 + g * 4) = o;
      }
  }
}

__global__ void sentinel_kernel(float* out) { out[0] = 1.0e9f; }

extern "C" void kernel_launch(void* const* d_in, const int* in_sizes, int n_in,
                              void* d_out, int out_size, void* d_ws, size_t ws_size,
                              hipStream_t stream) {
  const float* query = (const float*)d_in[0];
  const float* key   = (const float*)d_in[1];
  const float* value = (const float*)d_in[2];
  const float* Wq = (const float*)d_in[3];
  const float* bq = (const float*)d_in[4];
  const float* Wk = (const float*)d_in[5];
  const float* bk = (const float*)d_in[6];
  const float* Wv = (const float*)d_in[7];
  const float* bv = (const float*)d_in[8];
  const float* Wo = (const float*)d_in[9];
  const float* bo = (const float*)d_in[10];
  float* out = (float*)d_out;
  char* ws = (char*)d_ws;

  if (ws_size < (size_t)WS_NEEDED) {
    sentinel_kernel<<<1, 1, 0, stream>>>(out);
    return;
  }

  u16* part   = (u16*)(ws + PART_OFF);
  float* sums = (float*)(ws + SUMS_OFF);
  float* ctx  = (float*)(ws + CTX_OFF);
  u16* WTk    = (u16*)(ws + WTK_OFF);
  u16* WTv    = (u16*)(ws + WTV_OFF);
  u16* WTq    = (u16*)(ws + WTQ_OFF);
  u16* MbigT  = (u16*)(ws + MBIGT_OFF);

  const dim3 blk256(256);
  wcvt_kernel<<<dim3(8, 8, 3), blk256, 0, stream>>>(Wk, Wv, Wq, WTk, WTv, WTq);
  phase1_kernel<<<dim3(4, 128), 512, 0, stream>>>(key, value, WTk, WTv, bk, bv, part, sums);
  reduce_kernel<<<dim3(16, 16), blk256, 0, stream>>>(part, sums, ctx);
  mbigT_kernel<<<dim3(8, 16), blk256, 0, stream>>>(ctx, Wo, MbigT);
  phase3_kernel<<<1024, 512, 0, stream>>>(query, WTq, bq, MbigT, bo, out);
}

// Round 10
// 233.433 us; speedup vs baseline: 1.8195x; 1.3133x over previous
//
#include <hip/hip_runtime.h>
#include <hip/hip_bf16.h>

// Linear attention (Shen 2018), B=2, N=16384, D=512, H=8, DK=64.
// Round 10 = Round 8 with the phase1 LDS overlap fixed: staged chunk is
// 32 rows x 512 k x bf16 = 32KB PER matrix; KA/VA now get 32KB each and
// ET/VT live above them (80KB total, 2 blocks/CU).

using u16 = unsigned short;
typedef __attribute__((ext_vector_type(8))) short bf16x8;
typedef __attribute__((ext_vector_type(4))) float f32x4;

#define D_MODEL 512
#define SEQ 16384

// SWZ fragment layout for a 512x512 bf16 operand consumed as mfma_16x16x32
// row-panels: element (col,k) at  cb16=col>>4, lc=col&15, ksm=k>>5, g=(k>>3)&3,
// j=k&7, lane=g*16+lc:  idx = cb16*8192 + ksm*512 + lane*8 + j   (u16 units)

// ---- ws layout (bytes) ----
#define PART_OFF 0u            // f32 [16 bh][64 grp][64 e][64 d] = 16,777,216
#define SUMS_OFF 16777216u     // f32 [16 bh][64 grp][64 d]       = 262,144
#define CTX_OFF  17039360u     // f32 [16][64 d][64 e]            = 262,144
#define WTKS_OFF 17301504u     // bf16 swz 512x512 = 524,288
#define WTVS_OFF 17825792u
#define WTQS_OFF 18350080u
#define MTS_OFF  18874368u     // bf16 swz [2]x512x512 = 1,048,576
#define WS_NEEDED 19922944u

__device__ __forceinline__ float bf2f(u16 u) {
  union { unsigned int i; float f; } x; x.i = ((unsigned int)u) << 16; return x.f;
}
__device__ __forceinline__ u16 f2bf(float f) {
  union { float ff; unsigned int i; } x; x.ff = f;
  unsigned int r = x.i + 0x7fffu + ((x.i >> 16) & 1u);  // RNE
  return (u16)(r >> 16);
}
__device__ __forceinline__ unsigned int pk2(float lo, float hi) {
  union { __hip_bfloat162 h; unsigned int u; } x;
  x.h = __float22bfloat162_rn(float2{lo, hi});
  return x.u;
}
__device__ __forceinline__ bf16x8 ldsrd(const u16* base, int row, int rowbytes,
                                        int kbyte, int mask) {
  return *(const bf16x8*)((const char*)base + row * rowbytes + (kbyte ^ ((row & mask) << 4)));
}
// LDS-only barrier (no vmcnt drain): safe because at every barrier the only
// in-flight vmem ops are register-destined loads or fire-and-forget stores.
__device__ __forceinline__ void bar_lgkm() {
  asm volatile("s_waitcnt lgkmcnt(0)" ::: "memory");
  __builtin_amdgcn_sched_barrier(0);
  __builtin_amdgcn_s_barrier();
  __builtin_amdgcn_sched_barrier(0);
}

// ------- transpose+convert W -> swizzled fragment-order bf16 panels ---------
__launch_bounds__(256)
__global__ void wcvt_kernel(const float* __restrict__ Wk, const float* __restrict__ Wv,
                            const float* __restrict__ Wq, u16* __restrict__ WTks,
                            u16* __restrict__ WTvs, u16* __restrict__ WTqs) {
  const float* in = blockIdx.z == 0 ? Wk : (blockIdx.z == 1 ? Wv : Wq);
  u16* out = blockIdx.z == 0 ? WTks : (blockIdx.z == 1 ? WTvs : WTqs);
  __shared__ float S[64][65];  // [k][col]
  const int t = threadIdx.x;
  const int k0 = blockIdx.y << 6, c0 = blockIdx.x << 6;
#pragma unroll
  for (int ii = 0; ii < 4; ++ii) {
    const int idx = t + ii * 256;
    const int r = idx >> 4, c4 = (idx & 15) << 2;
    const float4 v = *(const float4*)(in + (k0 + r) * D_MODEL + c0 + c4);
    S[r][c4] = v.x; S[r][c4 + 1] = v.y; S[r][c4 + 2] = v.z; S[r][c4 + 3] = v.w;
  }
  __syncthreads();
#pragma unroll
  for (int it = 0; it < 2; ++it) {
    const int fi = it * 256 + t;             // 0..511
    const int cb_loc = fi >> 7;              // 0..3
    const int ksm_loc = (fi >> 6) & 1;       // 0..1
    const int lane = fi & 63;
    const int col_loc = cb_loc * 16 + (lane & 15);
    const int kl0 = ksm_loc * 32 + (lane >> 4) * 8;
    union { bf16x8 v; u16 e[8]; } o;
#pragma unroll
    for (int jj = 0; jj < 8; ++jj) o.e[jj] = f2bf(S[kl0 + jj][col_loc]);
    const int cb16 = blockIdx.x * 4 + cb_loc;
    const int ksm = blockIdx.y * 2 + ksm_loc;
    *(bf16x8*)(out + cb16 * 8192 + ksm * 512 + lane * 8) = o.v;
  }
}

// ---------------- phase 1: K then V GEMM, reg-acc partials ------------------
// flat grid 512; remap: x=f&7 (XCD), j=f>>3; hp=j&3, y = x*16 + (j>>2).
// block: 8 waves = 2 heads (hloc=w>>2) x 4 col-quarters (cq=w&3); 8 chunks.
__launch_bounds__(512, 4)
__global__ void phase1_kernel(const float* __restrict__ key, const float* __restrict__ value,
                              const u16* __restrict__ WTks, const u16* __restrict__ WTvs,
                              const float* __restrict__ bkp, const float* __restrict__ bvp,
                              float* __restrict__ part, float* __restrict__ sums) {
  __shared__ __align__(16) u16 smem[40960];  // 80KB
  u16* KA = smem;            // [32 n][1024B] swz mask 7  (32KB)
  u16* VA = smem + 16384;    // [32 n][1024B]             (32KB)
  u16* ET = smem + 32768;    // [2 hloc][64 d][64B] swz mask 3 (8KB)
  u16* VT = smem + 36864;    // [2 hloc][64 e][64B]            (8KB)
  const int t = threadIdx.x;
  const int lane = t & 63, w = t >> 6;
  const int g = lane >> 4, lc = lane & 15;
  const int f = blockIdx.x;
  const int jj = f >> 3, xc = f & 7;
  const int hp = jj & 3;
  const int y = xc * 16 + (jj >> 2);         // 0..127
  const int hloc = w >> 2, cq = w & 3;
  const int h = hp * 2 + hloc;
  const int dl = cq * 16 + lc;
  const int b = y >> 6, grp = y & 63;
  const int bh = b * 8 + h;
  u16* ETh = ET + hloc * 2048;
  u16* VTh = VT + hloc * 2048;
  const u16* wtkb = WTks + (h * 4 + cq) * 8192;
  const u16* wtvb = WTvs + (h * 4 + cq) * 8192;
  const float bbk = bkp[h * 64 + dl];
  const float bbv = bvp[h * 64 + dl];
  const int srow = t >> 4, sc8 = t & 15;
  const int swoff = srow * 1024 + ((sc8 << 3) ^ ((srow & 7) << 4));

  f32x4 pacc[4];
#pragma unroll
  for (int em = 0; em < 4; ++em) pacc[em] = (f32x4){0.f, 0.f, 0.f, 0.f};
  float sp = 0.f;
  bf16x8 bB[16];

#pragma unroll 1
  for (int ci = 0; ci < 8; ++ci) {
    const int n0 = (y * 8 + ci) * 32;
    // ---- stage K,V chunk: coalesced f32 -> bf16 swizzled LDS ----
    {
      const float* kp = key + (size_t)(n0 + srow) * D_MODEL + sc8 * 4;
      const float* vp = value + (size_t)(n0 + srow) * D_MODEL + sc8 * 4;
      float4 lk[8], lv[8];
#pragma unroll
      for (int q = 0; q < 8; ++q) lk[q] = *(const float4*)(kp + q * 64);
#pragma unroll
      for (int q = 0; q < 8; ++q) lv[q] = *(const float4*)(vp + q * 64);
#pragma unroll
      for (int q = 0; q < 8; ++q) {
        *(uint2*)((char*)KA + swoff + q * 128) =
            make_uint2(pk2(lk[q].x, lk[q].y), pk2(lk[q].z, lk[q].w));
        *(uint2*)((char*)VA + swoff + q * 128) =
            make_uint2(pk2(lv[q].x, lv[q].y), pk2(lv[q].z, lv[q].w));
      }
    }
    bar_lgkm();

    // ---- K projection: B panel (coalesced from L2) + GEMM ----
#pragma unroll
    for (int ks = 0; ks < 16; ++ks) bB[ks] = *(const bf16x8*)(wtkb + ks * 512 + lane * 8);
    f32x4 a0 = (f32x4){0.f, 0.f, 0.f, 0.f}, a1 = a0;
#pragma unroll
    for (int ks = 0; ks < 16; ++ks) {
      const int kb = ks * 64 + g * 16;
      bf16x8 ak0 = ldsrd(KA, lc, 1024, kb, 7);
      bf16x8 ak1 = ldsrd(KA, 16 + lc, 1024, kb, 7);
      a0 = __builtin_amdgcn_mfma_f32_16x16x32_bf16(ak0, bB[ks], a0, 0, 0, 0);
      a1 = __builtin_amdgcn_mfma_f32_16x16x32_bf16(ak1, bB[ks], a1, 0, 0, 0);
    }
    // E epilogue: exp, colsum accumulate, E^T strip -> ETh
    {
#pragma unroll
      for (int r = 0; r < 4; ++r) { a0[r] = __expf(a0[r] + bbk); sp += a0[r]; }
#pragma unroll
      for (int r = 0; r < 4; ++r) { a1[r] = __expf(a1[r] + bbk); sp += a1[r]; }
      *(uint2*)((char*)ETh + dl * 64 + ((g * 8) ^ ((dl & 3) << 4))) =
          make_uint2(pk2(a0[0], a0[1]), pk2(a0[2], a0[3]));
      *(uint2*)((char*)ETh + dl * 64 + ((32 + g * 8) ^ ((dl & 3) << 4))) =
          make_uint2(pk2(a1[0], a1[1]), pk2(a1[2], a1[3]));
    }
    // ---- V projection: reuse B regs ----
#pragma unroll
    for (int ks = 0; ks < 16; ++ks) bB[ks] = *(const bf16x8*)(wtvb + ks * 512 + lane * 8);
    a0 = (f32x4){0.f, 0.f, 0.f, 0.f}; a1 = a0;
#pragma unroll
    for (int ks = 0; ks < 16; ++ks) {
      const int kb = ks * 64 + g * 16;
      bf16x8 av0 = ldsrd(VA, lc, 1024, kb, 7);
      bf16x8 av1 = ldsrd(VA, 16 + lc, 1024, kb, 7);
      a0 = __builtin_amdgcn_mfma_f32_16x16x32_bf16(av0, bB[ks], a0, 0, 0, 0);
      a1 = __builtin_amdgcn_mfma_f32_16x16x32_bf16(av1, bB[ks], a1, 0, 0, 0);
    }
    *(uint2*)((char*)VTh + dl * 64 + ((g * 8) ^ ((dl & 3) << 4))) =
        make_uint2(pk2(a0[0] + bbv, a0[1] + bbv), pk2(a0[2] + bbv, a0[3] + bbv));
    *(uint2*)((char*)VTh + dl * 64 + ((32 + g * 8) ^ ((dl & 3) << 4))) =
        make_uint2(pk2(a1[0] + bbv, a1[1] + bbv), pk2(a1[2] + bbv, a1[3] + bbv));
    bar_lgkm();  // ET/VT complete across the head's 4 waves

    // ---- partial E^T V (k = 32 rows) accumulated into pacc ----
    {
      bf16x8 paf = ldsrd(ETh, dl, 64, g * 16, 3);
#pragma unroll
      for (int em = 0; em < 4; ++em) {
        bf16x8 pbf = ldsrd(VTh, em * 16 + lc, 64, g * 16, 3);
        pacc[em] = __builtin_amdgcn_mfma_f32_16x16x32_bf16(paf, pbf, pacc[em], 0, 0, 0);
      }
    }
    bar_lgkm();  // partial reads done before next chunk overwrites ET/VT
  }

  // ---- one store per block: f32 partials [e][d] + colsums ----
  float* pp = part + (size_t)(bh * 64 + grp) * 4096;
#pragma unroll
  for (int em = 0; em < 4; ++em)
    *(f32x4*)(pp + (em * 16 + lc) * 64 + cq * 16 + g * 4) = pacc[em];
  sp += __shfl_xor(sp, 16); sp += __shfl_xor(sp, 32);
  if (g == 0) sums[(size_t)(bh * 64 + grp) * 64 + dl] = sp;
}

// ---------------- phase 2: reduce partials -> ctx[d][e] ---------------------
__launch_bounds__(256)
__global__ void reduce_kernel(const float* __restrict__ part, const float* __restrict__ sums,
                              float* __restrict__ ctx) {
  __shared__ float den[64];
  const int bh = blockIdx.x;
  const int t = threadIdx.x;
  if (t < 64) {
    float s = 0.f;
    for (int gp = 0; gp < 64; ++gp) s += sums[(size_t)(bh * 64 + gp) * 64 + t];
    den[t] = s;
  }
  float4 A0 = {0,0,0,0}, A1 = {0,0,0,0}, A2 = {0,0,0,0}, A3 = {0,0,0,0};
  const float* pb = part + (size_t)bh * 64 * 4096;
  for (int gp = 0; gp < 64; ++gp) {
    const float4* q = (const float4*)(pb + gp * 4096 + t * 16);
    const float4 q0 = q[0], q1 = q[1], q2 = q[2], q3 = q[3];
    A0.x += q0.x; A0.y += q0.y; A0.z += q0.z; A0.w += q0.w;
    A1.x += q1.x; A1.y += q1.y; A1.z += q1.z; A1.w += q1.w;
    A2.x += q2.x; A2.y += q2.y; A2.z += q2.z; A2.w += q2.w;
    A3.x += q3.x; A3.y += q3.y; A3.z += q3.z; A3.w += q3.w;
  }
  __syncthreads();
  // positions p = t*16 + i in [e][d]: e = t>>2, d = (t&3)*16 + i
  const int e = t >> 2, d0 = (t & 3) * 16;
  float* cb = ctx + (size_t)bh * 4096 + e;
  const float r0[4] = {A0.x, A0.y, A0.z, A0.w};
  const float r1[4] = {A1.x, A1.y, A1.z, A1.w};
  const float r2[4] = {A2.x, A2.y, A2.z, A2.w};
  const float r3[4] = {A3.x, A3.y, A3.z, A3.w};
#pragma unroll
  for (int i = 0; i < 4; ++i) cb[(d0 + i) * 64] = r0[i] / den[d0 + i];
#pragma unroll
  for (int i = 0; i < 4; ++i) cb[(d0 + 4 + i) * 64] = r1[i] / den[d0 + 4 + i];
#pragma unroll
  for (int i = 0; i < 4; ++i) cb[(d0 + 8 + i) * 64] = r2[i] / den[d0 + 8 + i];
#pragma unroll
  for (int i = 0; i < 4; ++i) cb[(d0 + 12 + i) * 64] = r3[i] / den[d0 + 12 + i];
}

// -------- MTs (swizzled) = (ctx_h @ Wo_h)^T per batch -----------------------
__launch_bounds__(256)
__global__ void mbigT_kernel(const float* __restrict__ ctx, const float* __restrict__ Wo,
                             u16* __restrict__ MTs) {
  __shared__ float Clds[64][65];
  __shared__ float Wlds2[64][64];
  const int t = threadIdx.x;
  const int tx = t & 15, ty = t >> 4;
  const int cc = blockIdx.x;
  const int bh = blockIdx.y;
  const int b = bh >> 3, h = bh & 7;
  const float* ch = ctx + bh * 4096;
  for (int i4 = t; i4 < 1024; i4 += 256) {
    const int r = i4 >> 4, c = (i4 & 15) << 2;
    const float4 v = *(const float4*)(ch + (r << 6) + c);
    Clds[r][c] = v.x; Clds[r][c + 1] = v.y; Clds[r][c + 2] = v.z; Clds[r][c + 3] = v.w;
    const float4 wv = *(const float4*)(Wo + (h * 64 + r) * D_MODEL + cc * 64 + c);
    Wlds2[r][c] = wv.x; Wlds2[r][c + 1] = wv.y; Wlds2[r][c + 2] = wv.z; Wlds2[r][c + 3] = wv.w;
  }
  __syncthreads();
  float acc[4][4] = {};
#pragma unroll 8
  for (int k = 0; k < 64; ++k) {
    float a[4], wv[4];
#pragma unroll
    for (int i = 0; i < 4; ++i) a[i] = Clds[(ty << 2) + i][k];
#pragma unroll
    for (int j = 0; j < 4; ++j) wv[j] = Wlds2[k][(tx << 2) + j];
#pragma unroll
    for (int i = 0; i < 4; ++i)
#pragma unroll
      for (int j = 0; j < 4; ++j) acc[i][j] = fmaf(a[i], wv[j], acc[i][j]);
  }
  // scattered swizzled-layout stores (tiny kernel)
#pragma unroll
  for (int i = 0; i < 4; ++i)
#pragma unroll
    for (int j = 0; j < 4; ++j) {
      const int c = cc * 64 + (tx << 2) + j;      // out col
      const int k = h * 64 + (ty << 2) + i;       // k dim
      const int cb16 = c >> 4, lcc = c & 15;
      const int ksm = k >> 5, gg = (k >> 3) & 3, jb = k & 7;
      MTs[(size_t)b * 262144 + cb16 * 8192 + ksm * 512 + (gg * 16 + lcc) * 8 + jb]
          = f2bf(acc[i][j]);
    }
}

// ---------------- phase 3: Q pipeline + softmax + out-GEMM ------------------
__launch_bounds__(512, 2)
__global__ void phase3_kernel(const float* __restrict__ query, const u16* __restrict__ WTqs,
                              const float* __restrict__ bqp, const u16* __restrict__ MTs,
                              const float* __restrict__ bop, float* __restrict__ out) {
  __shared__ __align__(16) u16 smem[20480];  // 40KB
  u16* SL = smem;          // [2][2048] Q slices
  u16* P  = smem + 4096;   // [32 n][512 d], rows 1024B, swz mask 7
  const int t = threadIdx.x;
  const int lane = t & 63, w = t >> 6;
  const int g = lane >> 4, lc = lane & 15;
  const int chunk = blockIdx.x;
  const int n0 = chunk * 32;
  const int b = chunk >> 9;
  const int c0 = w * 64;
  const int srow = t >> 4;
  const int scol = (t & 15) << 2;
  const int sbyte = srow * 128 + (((t & 15) << 3) ^ ((srow & 7) << 4));
  const float* qbase = query + (size_t)(n0 + srow) * D_MODEL + scol;

  float4 lq[2];
  f32x4 acc[4][2];
#pragma unroll
  for (int m = 0; m < 4; ++m)
#pragma unroll
    for (int n = 0; n < 2; ++n) acc[m][n] = (f32x4){0.f, 0.f, 0.f, 0.f};

  lq[0] = *(const float4*)(qbase);
  lq[1] = *(const float4*)(qbase + 64);
  *(uint2*)((char*)SL + sbyte) = make_uint2(pk2(lq[0].x, lq[0].y), pk2(lq[0].z, lq[0].w));
  bar_lgkm();

#pragma unroll
  for (int ks = 0; ks < 8; ++ks) {
    if (ks + 2 < 8) lq[ks & 1] = *(const float4*)(qbase + (ks + 2) * 64);
    if (ks + 1 < 8) {
      const int p = (ks + 1) & 1;
      *(uint2*)((char*)SL + p * 4096 + sbyte) =
          make_uint2(pk2(lq[p].x, lq[p].y), pk2(lq[p].z, lq[p].w));
    }
    const u16* S = SL + (ks & 1) * 2048;
#pragma unroll
    for (int kk = 0; kk < 2; ++kk) {
      const int ksm = ks * 2 + kk;
      bf16x8 af[4], bfr[2];
#pragma unroll
      for (int mf = 0; mf < 4; ++mf)
        af[mf] = *(const bf16x8*)(WTqs + (w * 4 + mf) * 8192 + ksm * 512 + lane * 8);
#pragma unroll
      for (int nf = 0; nf < 2; ++nf) bfr[nf] = ldsrd(S, nf * 16 + lc, 128, kk * 64 + g * 16, 7);
#pragma unroll
      for (int mf = 0; mf < 4; ++mf)
#pragma unroll
        for (int nf = 0; nf < 2; ++nf)
          acc[mf][nf] = __builtin_amdgcn_mfma_f32_16x16x32_bf16(af[mf], bfr[nf], acc[mf][nf], 0, 0, 0);
    }
    bar_lgkm();
  }
  // ---- softmax over d (per n), *1/8, bf16 -> P ----
  {
    float bqv[4][4];
#pragma unroll
    for (int m = 0; m < 4; ++m)
#pragma unroll
      for (int r = 0; r < 4; ++r) bqv[m][r] = bqp[c0 + m * 16 + g * 4 + r];
#pragma unroll
    for (int nf = 0; nf < 2; ++nf) {
      float mx = -3.0e38f;
#pragma unroll
      for (int m = 0; m < 4; ++m)
#pragma unroll
        for (int r = 0; r < 4; ++r) {
          const float v = acc[m][nf][r] + bqv[m][r];
          acc[m][nf][r] = v; mx = fmaxf(mx, v);
        }
      mx = fmaxf(mx, __shfl_xor(mx, 16)); mx = fmaxf(mx, __shfl_xor(mx, 32));
      float s = 0.f;
#pragma unroll
      for (int m = 0; m < 4; ++m)
#pragma unroll
        for (int r = 0; r < 4; ++r) {
          const float e = __expf(acc[m][nf][r] - mx);
          acc[m][nf][r] = e; s += e;
        }
      s += __shfl_xor(s, 16); s += __shfl_xor(s, 32);
      const float fsc = 0.125f / s;
      const int n = nf * 16 + lc;
#pragma unroll
      for (int m = 0; m < 4; ++m) {
        const uint2 pw = make_uint2(pk2(acc[m][nf][0] * fsc, acc[m][nf][1] * fsc),
                                    pk2(acc[m][nf][2] * fsc, acc[m][nf][3] * fsc));
        *(uint2*)((char*)P + n * 1024 + ((w * 128 + m * 32 + g * 8) ^ ((n & 7) << 4))) = pw;
      }
    }
  }
  bar_lgkm();
  // ---- out^T = Mbig^T[b] @ P^T ----
  f32x4 oc[4][2];
#pragma unroll
  for (int m = 0; m < 4; ++m)
#pragma unroll
    for (int n = 0; n < 2; ++n) oc[m][n] = (f32x4){0.f, 0.f, 0.f, 0.f};
  const u16* MT = MTs + (size_t)b * 262144;
#pragma unroll 2
  for (int ks = 0; ks < 16; ++ks) {
    bf16x8 af[4], bfr[2];
#pragma unroll
    for (int mf = 0; mf < 4; ++mf)
      af[mf] = *(const bf16x8*)(MT + (w * 4 + mf) * 8192 + ks * 512 + lane * 8);
#pragma unroll
    for (int nf = 0; nf < 2; ++nf) bfr[nf] = ldsrd(P, nf * 16 + lc, 1024, ks * 64 + g * 16, 7);
#pragma unroll
    for (int mf = 0; mf < 4; ++mf)
#pragma unroll
      for (int nf = 0; nf < 2; ++nf)
        oc[mf][nf] = __builtin_amdgcn_mfma_f32_16x16x32_bf16(af[mf], bfr[nf], oc[mf][nf], 0, 0, 0);
  }
  {
    float bov[4][4];
#pragma unroll
    for (int m = 0; m < 4; ++m)
#pragma unroll
      for (int r = 0; r < 4; ++r) bov[m][r] = bop[c0 + m * 16 + g * 4 + r];
#pragma unroll
    for (int mf = 0; mf < 4; ++mf)
#pragma unroll
      for (int nf = 0; nf < 2; ++nf) {
        float4 o;
        o.x = oc[mf][nf][0] + bov[mf][0]; o.y = oc[mf][nf][1] + bov[mf][1];
        o.z = oc[mf][nf][2] + bov[mf][2]; o.w = oc[mf][nf][3] + bov[mf][3];
        *(float4*)(out + (size_t)(n0 + nf * 16 + lc) * D_MODEL + c0 + mf * 16 + g * 4) = o;
      }
  }
}

__global__ void sentinel_kernel(float* out) { out[0] = 1.0e9f; }

extern "C" void kernel_launch(void* const* d_in, const int* in_sizes, int n_in,
                              void* d_out, int out_size, void* d_ws, size_t ws_size,
                              hipStream_t stream) {
  const float* query = (const float*)d_in[0];
  const float* key   = (const float*)d_in[1];
  const float* value = (const float*)d_in[2];
  const float* Wq = (const float*)d_in[3];
  const float* bq = (const float*)d_in[4];
  const float* Wk = (const float*)d_in[5];
  const float* bk = (const float*)d_in[6];
  const float* Wv = (const float*)d_in[7];
  const float* bv = (const float*)d_in[8];
  const float* Wo = (const float*)d_in[9];
  const float* bo = (const float*)d_in[10];
  float* out = (float*)d_out;
  char* ws = (char*)d_ws;

  if (ws_size < (size_t)WS_NEEDED) {
    sentinel_kernel<<<1, 1, 0, stream>>>(out);
    return;
  }

  float* part = (float*)(ws + PART_OFF);
  float* sums = (float*)(ws + SUMS_OFF);
  float* ctx  = (float*)(ws + CTX_OFF);
  u16* WTks   = (u16*)(ws + WTKS_OFF);
  u16* WTvs   = (u16*)(ws + WTVS_OFF);
  u16* WTqs   = (u16*)(ws + WTQS_OFF);
  u16* MTs    = (u16*)(ws + MTS_OFF);

  const dim3 blk256(256);
  wcvt_kernel<<<dim3(8, 8, 3), blk256, 0, stream>>>(Wk, Wv, Wq, WTks, WTvs, WTqs);
  phase1_kernel<<<512, 512, 0, stream>>>(key, value, WTks, WTvs, bk, bv, part, sums);
  reduce_kernel<<<16, blk256, 0, stream>>>(part, sums, ctx);
  mbigT_kernel<<<dim3(8, 16), blk256, 0, stream>>>(ctx, Wo, MTs);
  phase3_kernel<<<1024, 512, 0, stream>>>(query, WTqs, bq, MTs, bo, out);
}